// Round 1
// baseline (2996.556 us; speedup 1.0000x reference)
//
#include <hip/hip_runtime.h>
#include <hip/hip_bf16.h>

// Problem: B=8192, D=H=4096, all fp32.
// out = (1-z)*hidden + z*n, with
//   r = sig(in·(w_ir+w_hr)^T + b_ir+b_hr)
//   z = sig(in·(w_iz+w_hz)^T + b_iz+b_hz)
//   n = sig(in·w_in^T + b_in + r * (in·w_hn^T + b_hn))
// => 4 effective GEMMs sharing the A (input) operand; combine fused in epilogue.

#define BM 128
#define BN 128
#define BK 32
#define THREADS 512
#define B_DIM 8192
#define D_DIM 4096
#define H_DIM 4096
#define NSTEP (D_DIM / BK)   // 128

typedef __attribute__((ext_vector_type(8))) short bf16x8;
typedef __attribute__((ext_vector_type(4))) float f32x4;
typedef __attribute__((ext_vector_type(4))) int i32x4;

__device__ __forceinline__ unsigned f2bf(float f) {
    union { float f; unsigned u; } v; v.f = f;
    // round-to-nearest-even bf16 (inputs are finite/well-scaled)
    return (v.u + 0x7FFFu + ((v.u >> 16) & 1u)) >> 16;
}
__device__ __forceinline__ unsigned pk(float a, float b) {
    return (f2bf(a) & 0xFFFFu) | (f2bf(b) << 16);
}
__device__ __forceinline__ i32x4 pack8(float4 x, float4 y) {
    i32x4 r;
    r[0] = (int)pk(x.x, x.y);
    r[1] = (int)pk(x.z, x.w);
    r[2] = (int)pk(y.x, y.y);
    r[3] = (int)pk(y.z, y.w);
    return r;
}
__device__ __forceinline__ float sigmoidf_(float x) {
    return 1.0f / (1.0f + __expf(-x));
}

// LDS layout per buffer (ints): A[0..2048) Br[2048..4096) Bz[..6144) Bn[..8192) Bh[..10240)
// Each region = 8 fragments (16 rows x 32 k) in fragment-contiguous form:
// frag f occupies f*256..f*256+256 ints; lane l's 16B at byte offset l*16.
// Element chunk (row r in frag, k-chunk c of 8) lives at lane c*16 + (r&15).

__global__ __launch_bounds__(THREADS, 2) void gru_fused(
    const float* __restrict__ input, const float* __restrict__ hidden,
    const float* __restrict__ w_ir, const float* __restrict__ b_ir,
    const float* __restrict__ w_iz, const float* __restrict__ b_iz,
    const float* __restrict__ w_in, const float* __restrict__ b_in,
    const float* __restrict__ w_hr, const float* __restrict__ b_hr,
    const float* __restrict__ w_hz, const float* __restrict__ b_hz,
    const float* __restrict__ w_hn, const float* __restrict__ b_hn,
    float* __restrict__ out)
{
    __shared__ int smem[2 * 10240];   // 80 KB, double-buffered

    const int tid  = threadIdx.x;
    const int lane = tid & 63;
    const int wid  = tid >> 6;
    const int wm   = wid >> 2;   // 0..1 : M-wave
    const int wn   = wid & 3;    // 0..3 : N-wave

    // b-fastest grid order: consecutive blocks share the h-panel (weight L2/L3 reuse)
    const int bblk = blockIdx.x & 63;
    const int hblk = blockIdx.x >> 6;
    const int b0 = bblk * BM;
    const int h0 = hblk * BN;

    // ---- staging assignment: thread t owns chunk (row = t>>2, k-chunk c = t&3)
    const int srow = tid >> 2;      // 0..127
    const int sc   = tid & 3;       // 0..3  (k offset = sc*8)
    const float4* gA  = (const float4*)(input + (size_t)(b0 + srow) * D_DIM + sc * 8);
    const size_t woff = (size_t)(h0 + srow) * D_DIM + sc * 8;
    const float4* gIr = (const float4*)(w_ir + woff);
    const float4* gHr = (const float4*)(w_hr + woff);
    const float4* gIz = (const float4*)(w_iz + woff);
    const float4* gHz = (const float4*)(w_hz + woff);
    const float4* gIn = (const float4*)(w_in + woff);
    const float4* gHn = (const float4*)(w_hn + woff);
    // LDS write offset (ints) within a region
    const int wr_ints = (srow >> 4) * 256 + ((sc * 16 + (srow & 15)) * 4);

    // accumulators: 4 gates x [mf 0..3][nf 0..1]
    f32x4 accR[4][2], accZ[4][2], accN[4][2], accH[4][2];
#pragma unroll
    for (int mf = 0; mf < 4; ++mf)
#pragma unroll
        for (int nf = 0; nf < 2; ++nf) {
            accR[mf][nf] = (f32x4)0.0f; accZ[mf][nf] = (f32x4)0.0f;
            accN[mf][nf] = (f32x4)0.0f; accH[mf][nf] = (f32x4)0.0f;
        }

    float4 La0, La1, Lr0, Lr1, Lr2, Lr3, Lz0, Lz1, Lz2, Lz3, Ln0, Ln1, Lh0, Lh1;

#define LOADREGS(s) do { const int o = (s) * 8;                          \
        La0 = gA[o];  La1 = gA[o + 1];                                   \
        Lr0 = gIr[o]; Lr1 = gIr[o + 1]; Lr2 = gHr[o]; Lr3 = gHr[o + 1];  \
        Lz0 = gIz[o]; Lz1 = gIz[o + 1]; Lz2 = gHz[o]; Lz3 = gHz[o + 1];  \
        Ln0 = gIn[o]; Ln1 = gIn[o + 1];                                  \
        Lh0 = gHn[o]; Lh1 = gHn[o + 1]; } while (0)

#define WRITELDS(pp) do { const int wb = (pp) * 10240 + wr_ints;          \
        *(i32x4*)&smem[wb]        = pack8(La0, La1);                      \
        *(i32x4*)&smem[wb + 2048] = pack8(Lr0 + Lr2, Lr1 + Lr3);          \
        *(i32x4*)&smem[wb + 4096] = pack8(Lz0 + Lz2, Lz1 + Lz3);          \
        *(i32x4*)&smem[wb + 6144] = pack8(Ln0, Ln1);                      \
        *(i32x4*)&smem[wb + 8192] = pack8(Lh0, Lh1); } while (0)

#define COMPUTE(pp) do {                                                  \
        const int cb = (pp) * 10240;                                      \
        const bf16x8* Af = (const bf16x8*)&smem[cb];                      \
        const bf16x8* Br = (const bf16x8*)&smem[cb + 2048];               \
        const bf16x8* Bz = (const bf16x8*)&smem[cb + 4096];               \
        const bf16x8* Bn = (const bf16x8*)&smem[cb + 6144];               \
        const bf16x8* Bh = (const bf16x8*)&smem[cb + 8192];               \
        bf16x8 afr[4];                                                    \
        _Pragma("unroll")                                                 \
        for (int mf = 0; mf < 4; ++mf)                                    \
            afr[mf] = Af[(wm * 4 + mf) * 64 + lane];                      \
        _Pragma("unroll")                                                 \
        for (int nf = 0; nf < 2; ++nf) {                                  \
            const int bi = (wn * 2 + nf) * 64 + lane;                     \
            bf16x8 fr = Br[bi], fz = Bz[bi], fn = Bn[bi], fh = Bh[bi];    \
            _Pragma("unroll")                                             \
            for (int mf = 0; mf < 4; ++mf) {                              \
                accR[mf][nf] = __builtin_amdgcn_mfma_f32_16x16x32_bf16(afr[mf], fr, accR[mf][nf], 0, 0, 0); \
                accZ[mf][nf] = __builtin_amdgcn_mfma_f32_16x16x32_bf16(afr[mf], fz, accZ[mf][nf], 0, 0, 0); \
                accN[mf][nf] = __builtin_amdgcn_mfma_f32_16x16x32_bf16(afr[mf], fn, accN[mf][nf], 0, 0, 0); \
                accH[mf][nf] = __builtin_amdgcn_mfma_f32_16x16x32_bf16(afr[mf], fh, accH[mf][nf], 0, 0, 0); \
            }                                                             \
        } } while (0)

    // prologue
    LOADREGS(0);
    WRITELDS(0);
    __syncthreads();

#pragma unroll 1
    for (int s = 0; s < NSTEP; ++s) {
        if (s + 1 < NSTEP) LOADREGS(s + 1);
        COMPUTE(s & 1);
        if (s + 1 < NSTEP) {
            WRITELDS((s + 1) & 1);
            __syncthreads();
        }
    }

    // ---- epilogue: biases + gate math + combine, fp32 out
    const int r4 = (lane >> 4) * 4;
    const int cn = lane & 15;
#pragma unroll
    for (int nf = 0; nf < 2; ++nf) {
        const int h = h0 + wn * 32 + nf * 16 + cn;
        const float br = b_ir[h] + b_hr[h];
        const float bz = b_iz[h] + b_hz[h];
        const float bn = b_in[h];
        const float bh = b_hn[h];
#pragma unroll
        for (int mf = 0; mf < 4; ++mf) {
            const int brow = b0 + wm * 64 + mf * 16 + r4;
#pragma unroll
            for (int j = 0; j < 4; ++j) {
                const size_t idx = (size_t)(brow + j) * H_DIM + h;
                const float sr = accR[mf][nf][j] + br;
                const float sz = accZ[mf][nf][j] + bz;
                const float sn = accN[mf][nf][j] + bn;
                const float sh = accH[mf][nf][j] + bh;
                const float r = sigmoidf_(sr);
                const float z = sigmoidf_(sz);
                const float n = sigmoidf_(sn + r * sh);
                out[idx] = (1.0f - z) * hidden[idx] + z * n;
            }
        }
    }
#undef LOADREGS
#undef WRITELDS
#undef COMPUTE
}

extern "C" void kernel_launch(void* const* d_in, const int* in_sizes, int n_in,
                              void* d_out, int out_size, void* d_ws, size_t ws_size,
                              hipStream_t stream) {
    const float* input  = (const float*)d_in[0];
    const float* hidden = (const float*)d_in[1];
    const float* w_ir = (const float*)d_in[2];  const float* b_ir = (const float*)d_in[3];
    const float* w_iz = (const float*)d_in[4];  const float* b_iz = (const float*)d_in[5];
    const float* w_in = (const float*)d_in[6];  const float* b_in = (const float*)d_in[7];
    const float* w_hr = (const float*)d_in[8];  const float* b_hr = (const float*)d_in[9];
    const float* w_hz = (const float*)d_in[10]; const float* b_hz = (const float*)d_in[11];
    const float* w_hn = (const float*)d_in[12]; const float* b_hn = (const float*)d_in[13];
    float* out = (float*)d_out;

    dim3 grid((B_DIM / BM) * (H_DIM / BN));   // 64 * 32 = 2048, b-fastest
    dim3 block(THREADS);
    gru_fused<<<grid, block, 0, stream>>>(input, hidden,
        w_ir, b_ir, w_iz, b_iz, w_in, b_in,
        w_hr, b_hr, w_hz, b_hz, w_hn, b_hn, out);
}

// Round 2
// 1504.959 us; speedup vs baseline: 1.9911x; 1.9911x over previous
//
#include <hip/hip_runtime.h>
#include <hip/hip_bf16.h>

// out = (1-z)*hidden + z*n
//   r = sig(in·(w_ir+w_hr)^T + b_ir+b_hr)
//   z = sig(in·(w_iz+w_hz)^T + b_iz+b_hz)
//   n = sig(in·w_in^T + b_in + r*(in·w_hn^T + b_hn))
// Fast path: prepass folds/converts weights+input to bf16 in d_ws, then a
// global_load_lds-staged, counted-vmcnt double-buffered 4-gate fused GEMM.
// Fallback (ws too small): round-1 fp32-staged kernel (known passing).

#define BM 128
#define BN 128
#define BK 32
#define THREADS 512
#define B_DIM 8192
#define D_DIM 4096
#define H_DIM 4096
#define NSTEP (D_DIM / BK)   // 128

// ws layout (bytes)
#define WS_WR 0
#define WS_WZ 33554432
#define WS_WN 67108864
#define WS_WH 100663296
#define WS_A  134217728
#define WS_NEED 201326592ULL

typedef __attribute__((ext_vector_type(8))) short bf16x8;
typedef __attribute__((ext_vector_type(4))) float f32x4;
typedef __attribute__((ext_vector_type(4))) int i32x4;

__device__ __forceinline__ unsigned f2bf(float f) {
    union { float f; unsigned u; } v; v.f = f;
    return (v.u + 0x7FFFu + ((v.u >> 16) & 1u)) >> 16;   // RNE
}
__device__ __forceinline__ unsigned pk(float a, float b) {
    return (f2bf(a) & 0xFFFFu) | (f2bf(b) << 16);
}
__device__ __forceinline__ i32x4 pack8(float4 x, float4 y) {
    i32x4 r;
    r[0] = (int)pk(x.x, x.y); r[1] = (int)pk(x.z, x.w);
    r[2] = (int)pk(y.x, y.y); r[3] = (int)pk(y.z, y.w);
    return r;
}
__device__ __forceinline__ float sigmoidf_(float x) {
    return 1.0f / (1.0f + __expf(-x));
}
__device__ __forceinline__ void gld16(const void* g, void* l) {
    __builtin_amdgcn_global_load_lds(
        (const __attribute__((address_space(1))) unsigned*)g,
        (__attribute__((address_space(3))) unsigned*)l, 16, 0, 0);
}

// ---------------- prepass kernels ----------------
__global__ __launch_bounds__(256) void prep_w(
    const float* __restrict__ ir, const float* __restrict__ hr,
    const float* __restrict__ iz, const float* __restrict__ hz,
    const float* __restrict__ inw, const float* __restrict__ hn,
    i32x4* __restrict__ wr, i32x4* __restrict__ wz,
    i32x4* __restrict__ wn, i32x4* __restrict__ wh)
{
    const int i = blockIdx.x * 256 + threadIdx.x;     // chunk of 8 floats
    const float4* pir = (const float4*)ir; const float4* phr = (const float4*)hr;
    const float4* piz = (const float4*)iz; const float4* phz = (const float4*)hz;
    const float4* pin = (const float4*)inw; const float4* phn = (const float4*)hn;
    float4 a0 = pir[2*i], a1 = pir[2*i+1], b0 = phr[2*i], b1 = phr[2*i+1];
    wr[i] = pack8(a0 + b0, a1 + b1);
    a0 = piz[2*i]; a1 = piz[2*i+1]; b0 = phz[2*i]; b1 = phz[2*i+1];
    wz[i] = pack8(a0 + b0, a1 + b1);
    wn[i] = pack8(pin[2*i], pin[2*i+1]);
    wh[i] = pack8(phn[2*i], phn[2*i+1]);
}

__global__ __launch_bounds__(256) void prep_a(const float* __restrict__ in,
                                              i32x4* __restrict__ a)
{
    const int i = blockIdx.x * 256 + threadIdx.x;
    const float4* p = (const float4*)in;
    a[i] = pack8(p[2*i], p[2*i+1]);
}

// ---------------- main bf16 kernel ----------------
// LDS per buffer (40960 B): A[0,8K) Br[8K,16K) Bz[16K,24K) Bn[24K,32K) Bh[32K,40K)
// Region = 8 frags of 1 KB; frag f = 16 rows x 32 k bf16, addr16 = f*64 + c*16 + r,
// i.e. linear in MFMA lane order -> DMA writes AND ds_read_b128 conflict-free.
__global__ __launch_bounds__(THREADS, 2) void gru_bf16(
    const char* __restrict__ Abf, const char* __restrict__ Wr,
    const char* __restrict__ Wz, const char* __restrict__ Wn,
    const char* __restrict__ Wh,
    const float* __restrict__ hidden,
    const float* __restrict__ b_ir, const float* __restrict__ b_iz,
    const float* __restrict__ b_in, const float* __restrict__ b_hr,
    const float* __restrict__ b_hz, const float* __restrict__ b_hn,
    float* __restrict__ out)
{
    __shared__ __attribute__((aligned(128))) char smem[2 * 40960];

    const int tid  = threadIdx.x;
    const int lane = tid & 63;
    const int wid  = tid >> 6;
    const int wm   = wid >> 2;   // 0..1
    const int wn   = wid & 3;    // 0..3

    const int bblk = blockIdx.x & 63;
    const int hblk = blockIdx.x >> 6;
    const int b0 = bblk * BM;
    const int h0 = hblk * BN;

    // staging: wave w stages frag w of each region; lane l -> row w*16+(l&15), k-chunk l>>4
    const int rA = b0 + wid * 16 + (lane & 15);
    const int rW = h0 + wid * 16 + (lane & 15);
    const size_t co = (size_t)(lane >> 4) * 16;     // chunk byte offset
    const char* gA = Abf + (size_t)rA * 8192 + co;
    const char* gR = Wr  + (size_t)rW * 8192 + co;
    const char* gZ = Wz  + (size_t)rW * 8192 + co;
    const char* gN = Wn  + (size_t)rW * 8192 + co;
    const char* gH = Wh  + (size_t)rW * 8192 + co;

    f32x4 accR[4][2], accZ[4][2], accN[4][2], accH[4][2];
#pragma unroll
    for (int mf = 0; mf < 4; ++mf)
#pragma unroll
        for (int nf = 0; nf < 2; ++nf) {
            accR[mf][nf] = (f32x4)0.0f; accZ[mf][nf] = (f32x4)0.0f;
            accN[mf][nf] = (f32x4)0.0f; accH[mf][nf] = (f32x4)0.0f;
        }

#define STAGE(s, p) do {                                        \
        const size_t kb = (size_t)(s) * 64;                     \
        char* lb = smem + (p) * 40960 + wid * 1024;             \
        gld16(gA + kb, lb);                                     \
        gld16(gR + kb, lb + 8192);                              \
        gld16(gZ + kb, lb + 16384);                             \
        gld16(gN + kb, lb + 24576);                             \
        gld16(gH + kb, lb + 32768);                             \
    } while (0)

#define MM(acc, a, b) acc = __builtin_amdgcn_mfma_f32_16x16x32_bf16(a, b, acc, 0, 0, 0)

    STAGE(0, 0);
    STAGE(1, 1);
    asm volatile("s_waitcnt vmcnt(5)" ::: "memory");
    __builtin_amdgcn_s_barrier();

#pragma unroll 1
    for (int s = 0; s < NSTEP; ++s) {
        const int p = s & 1;
        const char* cbp = smem + p * 40960;
        bf16x8 af[4], fbr[2], fbz[2], fbn[2], fbh[2];
#pragma unroll
        for (int mf = 0; mf < 4; ++mf)
            af[mf] = *(const bf16x8*)(cbp + (wm * 4 + mf) * 1024 + (lane << 4));
#pragma unroll
        for (int nf = 0; nf < 2; ++nf) {
            const int fo = (wn * 2 + nf) * 1024 + (lane << 4);
            fbr[nf] = *(const bf16x8*)(cbp + 8192  + fo);
            fbz[nf] = *(const bf16x8*)(cbp + 16384 + fo);
            fbn[nf] = *(const bf16x8*)(cbp + 24576 + fo);
            fbh[nf] = *(const bf16x8*)(cbp + 32768 + fo);
        }
        asm volatile("s_waitcnt lgkmcnt(0)" ::: "memory");
        __builtin_amdgcn_sched_barrier(0);
        __builtin_amdgcn_s_barrier();            // all waves done reading buf p
        if (s < NSTEP - 2) STAGE(s + 2, p);      // async overwrite of buf p
#pragma unroll
        for (int nf = 0; nf < 2; ++nf)
#pragma unroll
            for (int mf = 0; mf < 4; ++mf) {
                MM(accR[mf][nf], af[mf], fbr[nf]);
                MM(accZ[mf][nf], af[mf], fbz[nf]);
                MM(accN[mf][nf], af[mf], fbn[nf]);
                MM(accH[mf][nf], af[mf], fbh[nf]);
            }
        if (s < NSTEP - 2)      { asm volatile("s_waitcnt vmcnt(5)" ::: "memory"); }
        else if (s == NSTEP - 2){ asm volatile("s_waitcnt vmcnt(0)" ::: "memory"); }
        __builtin_amdgcn_s_barrier();            // buf[(s+1)&1] staged for next iter
    }

    const int r4 = (lane >> 4) * 4;
    const int cn = lane & 15;
#pragma unroll
    for (int nf = 0; nf < 2; ++nf) {
        const int h = h0 + wn * 32 + nf * 16 + cn;
        const float br = b_ir[h] + b_hr[h];
        const float bz = b_iz[h] + b_hz[h];
        const float bn = b_in[h];
        const float bh = b_hn[h];
#pragma unroll
        for (int mf = 0; mf < 4; ++mf) {
            const int brow = b0 + wm * 64 + mf * 16 + r4;
#pragma unroll
            for (int j = 0; j < 4; ++j) {
                const size_t idx = (size_t)(brow + j) * H_DIM + h;
                const float r = sigmoidf_(accR[mf][nf][j] + br);
                const float z = sigmoidf_(accZ[mf][nf][j] + bz);
                const float n = sigmoidf_(accN[mf][nf][j] + bn + r * (accH[mf][nf][j] + bh));
                out[idx] = (1.0f - z) * hidden[idx] + z * n;
            }
        }
    }
#undef STAGE
#undef MM
}

// ---------------- fallback: round-1 fp32-staged kernel (known passing) ----------------
__global__ __launch_bounds__(THREADS, 2) void gru_fused_f32(
    const float* __restrict__ input, const float* __restrict__ hidden,
    const float* __restrict__ w_ir, const float* __restrict__ b_ir,
    const float* __restrict__ w_iz, const float* __restrict__ b_iz,
    const float* __restrict__ w_in, const float* __restrict__ b_in,
    const float* __restrict__ w_hr, const float* __restrict__ b_hr,
    const float* __restrict__ w_hz, const float* __restrict__ b_hz,
    const float* __restrict__ w_hn, const float* __restrict__ b_hn,
    float* __restrict__ out)
{
    __shared__ int smem[2 * 10240];
    const int tid  = threadIdx.x;
    const int lane = tid & 63;
    const int wid  = tid >> 6;
    const int wm   = wid >> 2;
    const int wn   = wid & 3;
    const int bblk = blockIdx.x & 63;
    const int hblk = blockIdx.x >> 6;
    const int b0 = bblk * BM;
    const int h0 = hblk * BN;
    const int srow = tid >> 2;
    const int sc   = tid & 3;
    const float4* gA  = (const float4*)(input + (size_t)(b0 + srow) * D_DIM + sc * 8);
    const size_t woff = (size_t)(h0 + srow) * D_DIM + sc * 8;
    const float4* gIr = (const float4*)(w_ir + woff);
    const float4* gHr = (const float4*)(w_hr + woff);
    const float4* gIz = (const float4*)(w_iz + woff);
    const float4* gHz = (const float4*)(w_hz + woff);
    const float4* gIn = (const float4*)(w_in + woff);
    const float4* gHn = (const float4*)(w_hn + woff);
    const int wr_ints = (srow >> 4) * 256 + ((sc * 16 + (srow & 15)) * 4);

    f32x4 accR[4][2], accZ[4][2], accN[4][2], accH[4][2];
#pragma unroll
    for (int mf = 0; mf < 4; ++mf)
#pragma unroll
        for (int nf = 0; nf < 2; ++nf) {
            accR[mf][nf] = (f32x4)0.0f; accZ[mf][nf] = (f32x4)0.0f;
            accN[mf][nf] = (f32x4)0.0f; accH[mf][nf] = (f32x4)0.0f;
        }
    float4 La0, La1, Lr0, Lr1, Lr2, Lr3, Lz0, Lz1, Lz2, Lz3, Ln0, Ln1, Lh0, Lh1;
#define LOADREGS(s) do { const int o = (s) * 8;                          \
        La0 = gA[o];  La1 = gA[o + 1];                                   \
        Lr0 = gIr[o]; Lr1 = gIr[o + 1]; Lr2 = gHr[o]; Lr3 = gHr[o + 1];  \
        Lz0 = gIz[o]; Lz1 = gIz[o + 1]; Lz2 = gHz[o]; Lz3 = gHz[o + 1];  \
        Ln0 = gIn[o]; Ln1 = gIn[o + 1];                                  \
        Lh0 = gHn[o]; Lh1 = gHn[o + 1]; } while (0)
#define WRITELDS(pp) do { const int wb = (pp) * 10240 + wr_ints;          \
        *(i32x4*)&smem[wb]        = pack8(La0, La1);                      \
        *(i32x4*)&smem[wb + 2048] = pack8(Lr0 + Lr2, Lr1 + Lr3);          \
        *(i32x4*)&smem[wb + 4096] = pack8(Lz0 + Lz2, Lz1 + Lz3);          \
        *(i32x4*)&smem[wb + 6144] = pack8(Ln0, Ln1);                      \
        *(i32x4*)&smem[wb + 8192] = pack8(Lh0, Lh1); } while (0)
#define COMPUTE(pp) do {                                                  \
        const int cb = (pp) * 10240;                                      \
        const bf16x8* Af = (const bf16x8*)&smem[cb];                      \
        const bf16x8* Br = (const bf16x8*)&smem[cb + 2048];               \
        const bf16x8* Bz = (const bf16x8*)&smem[cb + 4096];               \
        const bf16x8* Bn = (const bf16x8*)&smem[cb + 6144];               \
        const bf16x8* Bh = (const bf16x8*)&smem[cb + 8192];               \
        bf16x8 afr[4];                                                    \
        _Pragma("unroll")                                                 \
        for (int mf = 0; mf < 4; ++mf)                                    \
            afr[mf] = Af[(wm * 4 + mf) * 64 + lane];                      \
        _Pragma("unroll")                                                 \
        for (int nf = 0; nf < 2; ++nf) {                                  \
            const int bi = (wn * 2 + nf) * 64 + lane;                     \
            bf16x8 fr = Br[bi], fz = Bz[bi], fn = Bn[bi], fh = Bh[bi];    \
            _Pragma("unroll")                                             \
            for (int mf = 0; mf < 4; ++mf) {                              \
                accR[mf][nf] = __builtin_amdgcn_mfma_f32_16x16x32_bf16(afr[mf], fr, accR[mf][nf], 0, 0, 0); \
                accZ[mf][nf] = __builtin_amdgcn_mfma_f32_16x16x32_bf16(afr[mf], fz, accZ[mf][nf], 0, 0, 0); \
                accN[mf][nf] = __builtin_amdgcn_mfma_f32_16x16x32_bf16(afr[mf], fn, accN[mf][nf], 0, 0, 0); \
                accH[mf][nf] = __builtin_amdgcn_mfma_f32_16x16x32_bf16(afr[mf], fh, accH[mf][nf], 0, 0, 0); \
            }                                                             \
        } } while (0)
    LOADREGS(0);
    WRITELDS(0);
    __syncthreads();
#pragma unroll 1
    for (int s = 0; s < NSTEP; ++s) {
        if (s + 1 < NSTEP) LOADREGS(s + 1);
        COMPUTE(s & 1);
        if (s + 1 < NSTEP) { WRITELDS((s + 1) & 1); __syncthreads(); }
    }
    const int r4 = (lane >> 4) * 4;
    const int cn = lane & 15;
#pragma unroll
    for (int nf = 0; nf < 2; ++nf) {
        const int h = h0 + wn * 32 + nf * 16 + cn;
        const float br = b_ir[h] + b_hr[h];
        const float bz = b_iz[h] + b_hz[h];
        const float bn = b_in[h];
        const float bh = b_hn[h];
#pragma unroll
        for (int mf = 0; mf < 4; ++mf) {
            const int brow = b0 + wm * 64 + mf * 16 + r4;
#pragma unroll
            for (int j = 0; j < 4; ++j) {
                const size_t idx = (size_t)(brow + j) * H_DIM + h;
                const float r = sigmoidf_(accR[mf][nf][j] + br);
                const float z = sigmoidf_(accZ[mf][nf][j] + bz);
                const float n = sigmoidf_(accN[mf][nf][j] + bn + r * (accH[mf][nf][j] + bh));
                out[idx] = (1.0f - z) * hidden[idx] + z * n;
            }
        }
    }
#undef LOADREGS
#undef WRITELDS
#undef COMPUTE
}

extern "C" void kernel_launch(void* const* d_in, const int* in_sizes, int n_in,
                              void* d_out, int out_size, void* d_ws, size_t ws_size,
                              hipStream_t stream) {
    const float* input  = (const float*)d_in[0];
    const float* hidden = (const float*)d_in[1];
    const float* w_ir = (const float*)d_in[2];  const float* b_ir = (const float*)d_in[3];
    const float* w_iz = (const float*)d_in[4];  const float* b_iz = (const float*)d_in[5];
    const float* w_in = (const float*)d_in[6];  const float* b_in = (const float*)d_in[7];
    const float* w_hr = (const float*)d_in[8];  const float* b_hr = (const float*)d_in[9];
    const float* w_hz = (const float*)d_in[10]; const float* b_hz = (const float*)d_in[11];
    const float* w_hn = (const float*)d_in[12]; const float* b_hn = (const float*)d_in[13];
    float* out = (float*)d_out;

    if (ws_size >= WS_NEED) {
        char* ws = (char*)d_ws;
        prep_w<<<dim3(8192), dim3(256), 0, stream>>>(
            w_ir, w_hr, w_iz, w_hz, w_in, w_hn,
            (i32x4*)(ws + WS_WR), (i32x4*)(ws + WS_WZ),
            (i32x4*)(ws + WS_WN), (i32x4*)(ws + WS_WH));
        prep_a<<<dim3(16384), dim3(256), 0, stream>>>(input, (i32x4*)(ws + WS_A));
        gru_bf16<<<dim3(2048), dim3(THREADS), 0, stream>>>(
            ws + WS_A, ws + WS_WR, ws + WS_WZ, ws + WS_WN, ws + WS_WH,
            hidden, b_ir, b_iz, b_in, b_hr, b_hz, b_hn, out);
    } else {
        gru_fused_f32<<<dim3(2048), dim3(THREADS), 0, stream>>>(
            input, hidden, w_ir, b_ir, w_iz, b_iz, w_in, b_in,
            w_hr, b_hr, w_hz, b_hz, w_hn, b_hn, out);
    }
}

// Round 3
// 1429.615 us; speedup vs baseline: 2.0961x; 1.0527x over previous
//
#include <hip/hip_runtime.h>
#include <hip/hip_bf16.h>

// out = (1-z)*hidden + z*n
//   r = sig(in·(w_ir+w_hr)^T + b_ir+b_hr)
//   z = sig(in·(w_iz+w_hz)^T + b_iz+b_hz)
//   n = sig(in·w_in^T + b_in + r*(in·w_hn^T + b_hn))
// Fast path: prepass folds/converts weights+input to bf16 in d_ws, then a
// global_load_lds-staged, phase-split (T3+T4+T5), counted-vmcnt double-buffered
// 4-gate fused GEMM with chunked XCD swizzle.
// Fallback (ws too small): round-1 fp32-staged kernel (known passing).

#define BM 128
#define BN 128
#define BK 32
#define THREADS 512
#define B_DIM 8192
#define D_DIM 4096
#define H_DIM 4096
#define NSTEP (D_DIM / BK)   // 128

// ws layout (bytes)
#define WS_WR 0
#define WS_WZ 33554432
#define WS_WN 67108864
#define WS_WH 100663296
#define WS_A  134217728
#define WS_NEED 201326592ULL

typedef __attribute__((ext_vector_type(8))) short bf16x8;
typedef __attribute__((ext_vector_type(4))) float f32x4;
typedef __attribute__((ext_vector_type(4))) int i32x4;

__device__ __forceinline__ unsigned f2bf(float f) {
    union { float f; unsigned u; } v; v.f = f;
    return (v.u + 0x7FFFu + ((v.u >> 16) & 1u)) >> 16;   // RNE
}
__device__ __forceinline__ unsigned pk(float a, float b) {
    return (f2bf(a) & 0xFFFFu) | (f2bf(b) << 16);
}
__device__ __forceinline__ i32x4 pack8(float4 x, float4 y) {
    i32x4 r;
    r[0] = (int)pk(x.x, x.y); r[1] = (int)pk(x.z, x.w);
    r[2] = (int)pk(y.x, y.y); r[3] = (int)pk(y.z, y.w);
    return r;
}
__device__ __forceinline__ float sigmoidf_(float x) {
    return 1.0f / (1.0f + __expf(-x));
}
__device__ __forceinline__ void gld16(const void* g, void* l) {
    __builtin_amdgcn_global_load_lds(
        (const __attribute__((address_space(1))) unsigned*)g,
        (__attribute__((address_space(3))) unsigned*)l, 16, 0, 0);
}

// ---------------- prepass kernels ----------------
__global__ __launch_bounds__(256) void prep_w(
    const float* __restrict__ ir, const float* __restrict__ hr,
    const float* __restrict__ iz, const float* __restrict__ hz,
    const float* __restrict__ inw, const float* __restrict__ hn,
    i32x4* __restrict__ wr, i32x4* __restrict__ wz,
    i32x4* __restrict__ wn, i32x4* __restrict__ wh)
{
    const int i = blockIdx.x * 256 + threadIdx.x;     // chunk of 8 floats
    const float4* pir = (const float4*)ir; const float4* phr = (const float4*)hr;
    const float4* piz = (const float4*)iz; const float4* phz = (const float4*)hz;
    const float4* pin = (const float4*)inw; const float4* phn = (const float4*)hn;
    float4 a0 = pir[2*i], a1 = pir[2*i+1], b0 = phr[2*i], b1 = phr[2*i+1];
    wr[i] = pack8(a0 + b0, a1 + b1);
    a0 = piz[2*i]; a1 = piz[2*i+1]; b0 = phz[2*i]; b1 = phz[2*i+1];
    wz[i] = pack8(a0 + b0, a1 + b1);
    wn[i] = pack8(pin[2*i], pin[2*i+1]);
    wh[i] = pack8(phn[2*i], phn[2*i+1]);
}

__global__ __launch_bounds__(256) void prep_a(const float* __restrict__ in,
                                              i32x4* __restrict__ a)
{
    const int i = blockIdx.x * 256 + threadIdx.x;
    const float4* p = (const float4*)in;
    a[i] = pack8(p[2*i], p[2*i+1]);
}

// ---------------- main bf16 kernel ----------------
// LDS per buffer (40960 B): A[0,8K) Br[8K,16K) Bz[16K,24K) Bn[24K,32K) Bh[32K,40K)
// Region = 8 frags of 1 KB; frag f = 16 rows x 32 k bf16, addr16 = f*64 + c*16 + r,
// i.e. linear in MFMA lane order -> DMA writes AND ds_read_b128 conflict-free.
// Per K-step: 2 phases (R,Z | N,H), each {reads, lgkm0, bar, stage-part, prio1,
// 16 MFMA, prio0}; counted vmcnt(5) at step end (T3+T4+T5).
__global__ __launch_bounds__(THREADS, 2) void gru_bf16(
    const char* __restrict__ Abf, const char* __restrict__ Wr,
    const char* __restrict__ Wz, const char* __restrict__ Wn,
    const char* __restrict__ Wh,
    const float* __restrict__ hidden,
    const float* __restrict__ b_ir, const float* __restrict__ b_iz,
    const float* __restrict__ b_in, const float* __restrict__ b_hr,
    const float* __restrict__ b_hz, const float* __restrict__ b_hn,
    float* __restrict__ out)
{
    __shared__ __attribute__((aligned(128))) char smem[2 * 40960];

    const int tid  = threadIdx.x;
    const int lane = tid & 63;
    const int wid  = tid >> 6;
    const int wm   = wid >> 2;   // 0..1
    const int wn   = wid & 3;    // 0..3

    // chunked XCD swizzle (nwg=2048, 8 XCDs, 256 blocks/XCD; bijective since 2048%8==0)
    // -> each XCD's co-resident blocks share ONE 4MB weight panel (fits its L2)
    const int nb  = (int)blockIdx.x;
    const int swz = (nb & 7) * 256 + (nb >> 3);
    const int bblk = swz & 63;
    const int hblk = swz >> 6;
    const int b0 = bblk * BM;
    const int h0 = hblk * BN;

    // staging: wave w stages frag w of each region; lane l -> row w*16+(l&15), k-chunk l>>4
    const int rA = b0 + wid * 16 + (lane & 15);
    const int rW = h0 + wid * 16 + (lane & 15);
    const size_t co = (size_t)(lane >> 4) * 16;     // chunk byte offset
    const char* gA = Abf + (size_t)rA * 8192 + co;
    const char* gR = Wr  + (size_t)rW * 8192 + co;
    const char* gZ = Wz  + (size_t)rW * 8192 + co;
    const char* gN = Wn  + (size_t)rW * 8192 + co;
    const char* gH = Wh  + (size_t)rW * 8192 + co;

    f32x4 accR[4][2], accZ[4][2], accN[4][2], accH[4][2];
#pragma unroll
    for (int mf = 0; mf < 4; ++mf)
#pragma unroll
        for (int nf = 0; nf < 2; ++nf) {
            accR[mf][nf] = (f32x4)0.0f; accZ[mf][nf] = (f32x4)0.0f;
            accN[mf][nf] = (f32x4)0.0f; accH[mf][nf] = (f32x4)0.0f;
        }

#define STAGE_ALL(s, p) do {                                    \
        const size_t kb = (size_t)(s) * 64;                     \
        char* lb0 = smem + (p) * 40960 + wid * 1024;            \
        gld16(gA + kb, lb0);                                    \
        gld16(gR + kb, lb0 + 8192);                             \
        gld16(gZ + kb, lb0 + 16384);                            \
        gld16(gN + kb, lb0 + 24576);                            \
        gld16(gH + kb, lb0 + 32768);                            \
    } while (0)

#define MM(acc, a, b) acc = __builtin_amdgcn_mfma_f32_16x16x32_bf16(a, b, acc, 0, 0, 0)

    STAGE_ALL(0, 0);
    STAGE_ALL(1, 1);
    asm volatile("s_waitcnt vmcnt(5)" ::: "memory");
    __builtin_amdgcn_s_barrier();

#pragma unroll 1
    for (int s = 0; s < NSTEP; ++s) {
        const int p = s & 1;
        const char* cbp = smem + p * 40960;
        char* lb = smem + p * 40960 + wid * 1024;
        const size_t kb2 = (size_t)(s + 2) * 64;
        const bool stg = (s < NSTEP - 2);

        bf16x8 af[4], fbr[2], fbz[2], fbn[2], fbh[2];
        // ---- P0 reads: A, R, Z (regions this phase will re-stage)
#pragma unroll
        for (int mf = 0; mf < 4; ++mf)
            af[mf] = *(const bf16x8*)(cbp + (wm * 4 + mf) * 1024 + (lane << 4));
#pragma unroll
        for (int nf = 0; nf < 2; ++nf) {
            const int fo = (wn * 2 + nf) * 1024 + (lane << 4);
            fbr[nf] = *(const bf16x8*)(cbp + 8192  + fo);
            fbz[nf] = *(const bf16x8*)(cbp + 16384 + fo);
        }
        asm volatile("s_waitcnt lgkmcnt(0)" ::: "memory");
        __builtin_amdgcn_sched_barrier(0);
        __builtin_amdgcn_s_barrier();            // all waves hold A,R,Z in regs
        if (stg) {                               // async overwrite A,R,Z of buf p (for s+2)
            gld16(gA + kb2, lb);
            gld16(gR + kb2, lb + 8192);
            gld16(gZ + kb2, lb + 16384);
        }
        // ---- P1 reads issued early (N,H regions are hazard-free all step)
#pragma unroll
        for (int nf = 0; nf < 2; ++nf) {
            const int fo = (wn * 2 + nf) * 1024 + (lane << 4);
            fbn[nf] = *(const bf16x8*)(cbp + 24576 + fo);
            fbh[nf] = *(const bf16x8*)(cbp + 32768 + fo);
        }
        __builtin_amdgcn_s_setprio(1);
#pragma unroll
        for (int nf = 0; nf < 2; ++nf)
#pragma unroll
            for (int mf = 0; mf < 4; ++mf) {
                MM(accR[mf][nf], af[mf], fbr[nf]);
                MM(accZ[mf][nf], af[mf], fbz[nf]);
            }
        __builtin_amdgcn_s_setprio(0);
        asm volatile("s_waitcnt lgkmcnt(0)" ::: "memory");
        __builtin_amdgcn_sched_barrier(0);
        __builtin_amdgcn_s_barrier();            // all waves hold N,H in regs
        if (stg) {                               // async overwrite N,H of buf p (for s+2)
            gld16(gN + kb2, lb + 24576);
            gld16(gH + kb2, lb + 32768);
        }
        __builtin_amdgcn_s_setprio(1);
#pragma unroll
        for (int nf = 0; nf < 2; ++nf)
#pragma unroll
            for (int mf = 0; mf < 4; ++mf) {
                MM(accN[mf][nf], af[mf], fbn[nf]);
                MM(accH[mf][nf], af[mf], fbh[nf]);
            }
        __builtin_amdgcn_s_setprio(0);
        if (stg)                  { asm volatile("s_waitcnt vmcnt(5)" ::: "memory"); }
        else if (s == NSTEP - 2)  { asm volatile("s_waitcnt vmcnt(0)" ::: "memory"); }
        __builtin_amdgcn_s_barrier();            // buf[(s+1)&1] fully staged
    }

    const int r4 = (lane >> 4) * 4;
    const int cn = lane & 15;
#pragma unroll
    for (int nf = 0; nf < 2; ++nf) {
        const int h = h0 + wn * 32 + nf * 16 + cn;
        const float br = b_ir[h] + b_hr[h];
        const float bz = b_iz[h] + b_hz[h];
        const float bn = b_in[h];
        const float bh = b_hn[h];
#pragma unroll
        for (int mf = 0; mf < 4; ++mf) {
            const int brow = b0 + wm * 64 + mf * 16 + r4;
#pragma unroll
            for (int j = 0; j < 4; ++j) {
                const size_t idx = (size_t)(brow + j) * H_DIM + h;
                const float r = sigmoidf_(accR[mf][nf][j] + br);
                const float z = sigmoidf_(accZ[mf][nf][j] + bz);
                const float n = sigmoidf_(accN[mf][nf][j] + bn + r * (accH[mf][nf][j] + bh));
                out[idx] = (1.0f - z) * hidden[idx] + z * n;
            }
        }
    }
#undef STAGE_ALL
#undef MM
}

// ---------------- fallback: round-1 fp32-staged kernel (known passing) ----------------
__global__ __launch_bounds__(THREADS, 2) void gru_fused_f32(
    const float* __restrict__ input, const float* __restrict__ hidden,
    const float* __restrict__ w_ir, const float* __restrict__ b_ir,
    const float* __restrict__ w_iz, const float* __restrict__ b_iz,
    const float* __restrict__ w_in, const float* __restrict__ b_in,
    const float* __restrict__ w_hr, const float* __restrict__ b_hr,
    const float* __restrict__ w_hz, const float* __restrict__ b_hz,
    const float* __restrict__ w_hn, const float* __restrict__ b_hn,
    float* __restrict__ out)
{
    __shared__ int smem[2 * 10240];
    const int tid  = threadIdx.x;
    const int lane = tid & 63;
    const int wid  = tid >> 6;
    const int wm   = wid >> 2;
    const int wn   = wid & 3;
    const int bblk = blockIdx.x & 63;
    const int hblk = blockIdx.x >> 6;
    const int b0 = bblk * BM;
    const int h0 = hblk * BN;
    const int srow = tid >> 2;
    const int sc   = tid & 3;
    const float4* gA  = (const float4*)(input + (size_t)(b0 + srow) * D_DIM + sc * 8);
    const size_t woff = (size_t)(h0 + srow) * D_DIM + sc * 8;
    const float4* gIr = (const float4*)(w_ir + woff);
    const float4* gHr = (const float4*)(w_hr + woff);
    const float4* gIz = (const float4*)(w_iz + woff);
    const float4* gHz = (const float4*)(w_hz + woff);
    const float4* gIn = (const float4*)(w_in + woff);
    const float4* gHn = (const float4*)(w_hn + woff);
    const int wr_ints = (srow >> 4) * 256 + ((sc * 16 + (srow & 15)) * 4);

    f32x4 accR[4][2], accZ[4][2], accN[4][2], accH[4][2];
#pragma unroll
    for (int mf = 0; mf < 4; ++mf)
#pragma unroll
        for (int nf = 0; nf < 2; ++nf) {
            accR[mf][nf] = (f32x4)0.0f; accZ[mf][nf] = (f32x4)0.0f;
            accN[mf][nf] = (f32x4)0.0f; accH[mf][nf] = (f32x4)0.0f;
        }
    float4 La0, La1, Lr0, Lr1, Lr2, Lr3, Lz0, Lz1, Lz2, Lz3, Ln0, Ln1, Lh0, Lh1;
#define LOADREGS(s) do { const int o = (s) * 8;                          \
        La0 = gA[o];  La1 = gA[o + 1];                                   \
        Lr0 = gIr[o]; Lr1 = gIr[o + 1]; Lr2 = gHr[o]; Lr3 = gHr[o + 1];  \
        Lz0 = gIz[o]; Lz1 = gIz[o + 1]; Lz2 = gHz[o]; Lz3 = gHz[o + 1];  \
        Ln0 = gIn[o]; Ln1 = gIn[o + 1];                                  \
        Lh0 = gHn[o]; Lh1 = gHn[o + 1]; } while (0)
#define WRITELDS(pp) do { const int wb = (pp) * 10240 + wr_ints;          \
        *(i32x4*)&smem[wb]        = pack8(La0, La1);                      \
        *(i32x4*)&smem[wb + 2048] = pack8(Lr0 + Lr2, Lr1 + Lr3);          \
        *(i32x4*)&smem[wb + 4096] = pack8(Lz0 + Lz2, Lz1 + Lz3);          \
        *(i32x4*)&smem[wb + 6144] = pack8(Ln0, Ln1);                      \
        *(i32x4*)&smem[wb + 8192] = pack8(Lh0, Lh1); } while (0)
#define COMPUTE(pp) do {                                                  \
        const int cb = (pp) * 10240;                                      \
        const bf16x8* Af = (const bf16x8*)&smem[cb];                      \
        const bf16x8* Br = (const bf16x8*)&smem[cb + 2048];               \
        const bf16x8* Bz = (const bf16x8*)&smem[cb + 4096];               \
        const bf16x8* Bn = (const bf16x8*)&smem[cb + 6144];               \
        const bf16x8* Bh = (const bf16x8*)&smem[cb + 8192];               \
        bf16x8 afr[4];                                                    \
        _Pragma("unroll")                                                 \
        for (int mf = 0; mf < 4; ++mf)                                    \
            afr[mf] = Af[(wm * 4 + mf) * 64 + lane];                      \
        _Pragma("unroll")                                                 \
        for (int nf = 0; nf < 2; ++nf) {                                  \
            const int bi = (wn * 2 + nf) * 64 + lane;                     \
            bf16x8 fr = Br[bi], fz = Bz[bi], fn = Bn[bi], fh = Bh[bi];    \
            _Pragma("unroll")                                             \
            for (int mf = 0; mf < 4; ++mf) {                              \
                accR[mf][nf] = __builtin_amdgcn_mfma_f32_16x16x32_bf16(afr[mf], fr, accR[mf][nf], 0, 0, 0); \
                accZ[mf][nf] = __builtin_amdgcn_mfma_f32_16x16x32_bf16(afr[mf], fz, accZ[mf][nf], 0, 0, 0); \
                accN[mf][nf] = __builtin_amdgcn_mfma_f32_16x16x32_bf16(afr[mf], fn, accN[mf][nf], 0, 0, 0); \
                accH[mf][nf] = __builtin_amdgcn_mfma_f32_16x16x32_bf16(afr[mf], fh, accH[mf][nf], 0, 0, 0); \
            }                                                             \
        } } while (0)
    LOADREGS(0);
    WRITELDS(0);
    __syncthreads();
#pragma unroll 1
    for (int s = 0; s < NSTEP; ++s) {
        if (s + 1 < NSTEP) LOADREGS(s + 1);
        COMPUTE(s & 1);
        if (s + 1 < NSTEP) { WRITELDS((s + 1) & 1); __syncthreads(); }
    }
    const int r4 = (lane >> 4) * 4;
    const int cn = lane & 15;
#pragma unroll
    for (int nf = 0; nf < 2; ++nf) {
        const int h = h0 + wn * 32 + nf * 16 + cn;
        const float br = b_ir[h] + b_hr[h];
        const float bz = b_iz[h] + b_hz[h];
        const float bn = b_in[h];
        const float bh = b_hn[h];
#pragma unroll
        for (int mf = 0; mf < 4; ++mf) {
            const int brow = b0 + wm * 64 + mf * 16 + r4;
#pragma unroll
            for (int j = 0; j < 4; ++j) {
                const size_t idx = (size_t)(brow + j) * H_DIM + h;
                const float r = sigmoidf_(accR[mf][nf][j] + br);
                const float z = sigmoidf_(accZ[mf][nf][j] + bz);
                const float n = sigmoidf_(accN[mf][nf][j] + bn + r * (accH[mf][nf][j] + bh));
                out[idx] = (1.0f - z) * hidden[idx] + z * n;
            }
        }
    }
#undef LOADREGS
#undef WRITELDS
#undef COMPUTE
}

extern "C" void kernel_launch(void* const* d_in, const int* in_sizes, int n_in,
                              void* d_out, int out_size, void* d_ws, size_t ws_size,
                              hipStream_t stream) {
    const float* input  = (const float*)d_in[0];
    const float* hidden = (const float*)d_in[1];
    const float* w_ir = (const float*)d_in[2];  const float* b_ir = (const float*)d_in[3];
    const float* w_iz = (const float*)d_in[4];  const float* b_iz = (const float*)d_in[5];
    const float* w_in = (const float*)d_in[6];  const float* b_in = (const float*)d_in[7];
    const float* w_hr = (const float*)d_in[8];  const float* b_hr = (const float*)d_in[9];
    const float* w_hz = (const float*)d_in[10]; const float* b_hz = (const float*)d_in[11];
    const float* w_hn = (const float*)d_in[12]; const float* b_hn = (const float*)d_in[13];
    float* out = (float*)d_out;

    if (ws_size >= WS_NEED) {
        char* ws = (char*)d_ws;
        prep_w<<<dim3(8192), dim3(256), 0, stream>>>(
            w_ir, w_hr, w_iz, w_hz, w_in, w_hn,
            (i32x4*)(ws + WS_WR), (i32x4*)(ws + WS_WZ),
            (i32x4*)(ws + WS_WN), (i32x4*)(ws + WS_WH));
        prep_a<<<dim3(16384), dim3(256), 0, stream>>>(input, (i32x4*)(ws + WS_A));
        gru_bf16<<<dim3(2048), dim3(THREADS), 0, stream>>>(
            ws + WS_A, ws + WS_WR, ws + WS_WZ, ws + WS_WN, ws + WS_WH,
            hidden, b_ir, b_iz, b_in, b_hr, b_hz, b_hn, out);
    } else {
        gru_fused_f32<<<dim3(2048), dim3(THREADS), 0, stream>>>(
            input, hidden, w_ir, b_ir, w_iz, b_iz, w_in, b_in,
            w_hr, b_hr, w_hz, b_hz, w_hn, b_hn, out);
    }
}